// Round 5
// baseline (2978.087 us; speedup 1.0000x reference)
//
#include <hip/hip_runtime.h>
#include <hip/hip_bf16.h>
#include <stdint.h>

// SNN forward (snntorch Leaky, subtract reset), T=1024 B=128 NIN=256 HID=1024.
// d_out: out_spikes [T,B,2] | hidden_spikes [T,B,HID] | mem2_f [B,2]
//
// Round-5: the gather is LDS-pipe bound and b32/b64 both deliver ~35-44 B/cy;
// only ds_read_b128 reaches ~85 B/cy. New k_snn: 4 j per lane (float4 quad),
// 128-j tile [256 i][128 j] = 128 KB LDS; ONE b128 serves TWO active indices
// (lanes 0-31 read row i_even, lanes 32-63 row i_odd); v_permlane32_swap_b32
// (VALU pipe, not DS) redistributes so every lane gets (E,O) for its quad.
// Accumulation order stays bias -> strictly ascending active i (h+=E; h+=O),
// mul-free -> hidden spikes bit-exact. k_pack/k_h2/k_scan unchanged.

#define TT  1024
#define BB  128
#define NIN 256
#define HID 1024

#define OFF_HID  262144ULL
#define OFF_MEM2 134479872ULL

__global__ __launch_bounds__(256) void k_transpose(const float* __restrict__ W1,
                                                   float* __restrict__ W1T) {
    int idx = blockIdx.x * 256 + threadIdx.x;     // 262144 elements
    int j = idx & (HID - 1);
    int i = idx >> 10;
    W1T[(size_t)i * HID + j] = W1[(size_t)j * NIN + i];
}

__global__ __launch_bounds__(256) void k_pack(const float* __restrict__ x,
                                              unsigned int* __restrict__ cntArr,
                                              unsigned char* __restrict__ idxArr,
                                              int slots) {
    size_t tb = blockIdx.x;                       // T*B blocks, 256 threads = i
    int tid = threadIdx.x;
    int lane = tid & 63, w = tid >> 6;
    float v = x[tb * NIN + tid];
    bool act = v > 0.5f;
    unsigned long long m = __ballot(act);
    __shared__ unsigned int wc[4];
    __shared__ unsigned char sIdx[96];
    if (lane == 0) wc[w] = (unsigned int)__popcll(m);
    __syncthreads();
    unsigned int off = 0;
#pragma unroll
    for (int k = 0; k < 4; ++k) if (k < w) off += wc[k];
    unsigned int cnt = wc[0] + wc[1] + wc[2] + wc[3];
    unsigned int rank = off + (unsigned int)__popcll(m & ((1ull << lane) - 1));
    if (act && rank < (unsigned int)slots) sIdx[rank] = (unsigned char)tid;
    __syncthreads();
    if (tid * 4 < slots)
        ((unsigned int*)(idxArr + tb * (size_t)slots))[tid] = ((const unsigned int*)sIdx)[tid];
    if (tid == 0) cntArr[tb] = cnt;
}

// Workgroup = 4 waves = 4 b's sharing a 128-j chunk of W1T as [256 i][32 quads]
// float4 (128 KB LDS). Lane handles quad (lane&31); half = lane>>5 picks the
// even/odd active row per paired b128. Grid = 32 bg x 8 jc = 256 wgs (1/CU).
__global__ __launch_bounds__(256, 1) void k_snn(const float* __restrict__ W1T,
                                                const unsigned int* __restrict__ cntArr,
                                                const unsigned char* __restrict__ idxArr,
                                                const float* __restrict__ x,
                                                const float* __restrict__ b1,
                                                float* __restrict__ outHid,
                                                int slots) {
#pragma clang fp contract(off)
    const int jc   = blockIdx.x & 7;
    const int bg   = blockIdx.x >> 3;
    const int lane = threadIdx.x & 63;
    const int wave = threadIdx.x >> 6;
    const int b    = (bg << 2) + wave;
    const int q    = lane & 31;                   // quad index within 128-j chunk
    const int half = lane >> 5;                   // 0: even idx row, 1: odd idx row
    const int jq   = (jc << 7) + (q << 2);        // first j of this lane's quad

    __shared__ float4 sW4[NIN * 32];              // 128 KB: [i][quad]
    for (int p = threadIdx.x; p < NIN * 32; p += 256) {
        int i = p >> 5, qq = p & 31;
        sW4[p] = *reinterpret_cast<const float4*>(W1T + (size_t)i * HID + (jc << 7) + (qq << 2));
    }
    __syncthreads();

    float mem0 = 0.0f, mem1 = 0.0f, mem2 = 0.0f, mem3 = 0.0f;
    const float4 bs = *reinterpret_cast<const float4*>(b1 + jq);
    const int    ub = __builtin_amdgcn_readfirstlane(b);

    // prefetch t=0 index data
    unsigned int cnt_v  = cntArr[(size_t)ub];
    unsigned int vIdx_v = ((const unsigned int*)(idxArr + (size_t)ub * (size_t)slots))[lane & 31];

    // pair p covers active indices (2p, 2p+1): lanes<32 read row idx[2p],
    // lanes>=32 read row idx[2p+1], each at its own quad.
#define ISSUE(p, dst) do {                                                            \
        unsigned int dw_ = (unsigned int)__builtin_amdgcn_readlane((int)vIdx, (int)((p) >> 1)); \
        unsigned int sh_ = ((p) & 1u) << 4;                                           \
        unsigned int e_  = (dw_ >> sh_) & 255u;                                       \
        unsigned int o_  = (dw_ >> (sh_ + 8)) & 255u;                                 \
        unsigned int row_ = half ? o_ : e_;                                           \
        dst = sW4[row_ * 32 + q];                                                     \
    } while (0)

    // swap halves per component (VALU): ex -> E value for all lanes, ox -> O.
#define CONSUME(v) do {                                                               \
        float ex_ = v.x, ox_ = v.x;                                                   \
        float ey_ = v.y, oy_ = v.y;                                                   \
        float ez_ = v.z, oz_ = v.z;                                                   \
        float ew_ = v.w, ow_ = v.w;                                                   \
        asm("v_permlane32_swap_b32 %0, %1" : "+v"(ex_), "+v"(ox_));                   \
        asm("v_permlane32_swap_b32 %0, %1" : "+v"(ey_), "+v"(oy_));                   \
        asm("v_permlane32_swap_b32 %0, %1" : "+v"(ez_), "+v"(oz_));                   \
        asm("v_permlane32_swap_b32 %0, %1" : "+v"(ew_), "+v"(ow_));                   \
        h0 += ex_; h0 += ox_;                                                         \
        h1 += ey_; h1 += oy_;                                                         \
        h2 += ez_; h2 += oz_;                                                         \
        h3 += ew_; h3 += ow_;                                                         \
    } while (0)

    for (int t = 0; t < TT; ++t) {
        unsigned int cnt  = (unsigned int)__builtin_amdgcn_readfirstlane((int)cnt_v);
        unsigned int vIdx = vIdx_v;

        // prefetch t+1 (clamped) — hides global latency under the gather
        int tn = (t + 1 < TT) ? t + 1 : t;
        size_t tbn = (size_t)tn * BB + ub;
        cnt_v  = cntArr[tbn];
        vIdx_v = ((const unsigned int*)(idxArr + tbn * (size_t)slots))[lane & 31];

        float h0 = bs.x, h1 = bs.y, h2 = bs.z, h3 = bs.w;
        unsigned int lim = cnt < (unsigned int)slots ? cnt : (unsigned int)slots;
        unsigned int nP  = lim >> 1;
        unsigned int rem = lim & 1u;

        float4 sA, sB;
        if (nP > 0) ISSUE(0u, sA);
        if (nP > 1) ISSUE(1u, sB);
        for (unsigned int p = 0; p < nP; ++p) {
            float4 cur = sA;
            sA = sB;
            if (p + 2 < nP) ISSUE(p + 2, sB);
            CONSUME(cur);
        }
        if (rem) {                                // last (even-positioned) index: broadcast
            unsigned int kk = lim - 1;
            unsigned int dw = (unsigned int)__builtin_amdgcn_readlane((int)vIdx, (int)(kk >> 2));
            unsigned int e  = (dw >> ((kk & 3u) * 8u)) & 255u;
            float4 v = sW4[e * 32 + q];
            h0 += v.x; h1 += v.y; h2 += v.z; h3 += v.w;
        }
        if (cnt > (unsigned int)slots) {          // ~never: overflow fallback
            const float* xr = x + ((size_t)t * BB + ub) * NIN;
            unsigned int skip = (unsigned int)slots;
            for (int w = 0; w < 4; ++w) {
                unsigned long long m = __ballot(xr[(w << 6) + lane] > 0.5f);
                unsigned int pc = (unsigned int)__popcll(m);
                if (skip >= pc) { skip -= pc; continue; }
                while (skip) { m &= m - 1; --skip; }
                while (m) {
                    int i = (w << 6) + __builtin_ctzll(m);
                    m &= m - 1;
                    float4 v = sW4[i * 32 + q];
                    h0 += v.x; h1 += v.y; h2 += v.z; h3 += v.w;
                }
            }
        }

        // membrane update (np fp32 semantics: mul, add separate)
        float mm0 = 0.9f * mem0; mm0 = mm0 + h0;
        float s0 = (mm0 - 1.0f > 0.0f) ? 1.0f : 0.0f;
        mm0 = mm0 - s0; mem0 = mm0;
        float mm1 = 0.9f * mem1; mm1 = mm1 + h1;
        float s1 = (mm1 - 1.0f > 0.0f) ? 1.0f : 0.0f;
        mm1 = mm1 - s1; mem1 = mm1;
        float mm2 = 0.9f * mem2; mm2 = mm2 + h2;
        float s2 = (mm2 - 1.0f > 0.0f) ? 1.0f : 0.0f;
        mm2 = mm2 - s2; mem2 = mm2;
        float mm3 = 0.9f * mem3; mm3 = mm3 + h3;
        float s3 = (mm3 - 1.0f > 0.0f) ? 1.0f : 0.0f;
        mm3 = mm3 - s3; mem3 = mm3;

        if (half == 0) {                          // halves hold identical results
            float4 sv; sv.x = s0; sv.y = s1; sv.z = s2; sv.w = s3;
            *reinterpret_cast<float4*>(outHid + (size_t)t * (BB * HID) + (size_t)b * HID + jq) = sv;
        }
    }
#undef ISSUE
#undef CONSUME
}

// One wave per (t,b): bit-identical layer-2 tree to rounds 1-4:
// per chunk c (ascending 0..15): r = spk[c*64+lane]*W2[o][c*64+lane],
// xor-butterfly offs 32,16,8,4,2,1, accumulate; then + b2[o].
__global__ __launch_bounds__(256) void k_h2(const float* __restrict__ spk,
                                            const float* __restrict__ W2,
                                            const float* __restrict__ b2,
                                            float* __restrict__ h2) {
#pragma clang fp contract(off)
    const int lane = threadIdx.x & 63;
    const int wave = threadIdx.x >> 6;
    size_t tb = (size_t)blockIdx.x * 4 + wave;    // t*B + b
    const float* row = spk + tb * HID;
    float s0 = 0.0f, s1 = 0.0f;
#pragma unroll
    for (int c = 0; c < 16; ++c) {
        float v  = row[c * 64 + lane];
        float r0 = v * W2[c * 64 + lane];
        float r1 = v * W2[HID + c * 64 + lane];
#pragma unroll
        for (int off = 32; off > 0; off >>= 1) {
            r0 += __shfl_xor(r0, off, 64);
            r1 += __shfl_xor(r1, off, 64);
        }
        s0 += r0;
        s1 += r1;
    }
    s0 += b2[0];
    s1 += b2[1];
    if (lane == 0)
        *reinterpret_cast<float2*>(h2 + tb * 2) = make_float2(s0, s1);
}

__global__ __launch_bounds__(256) void k_scan(const float* __restrict__ h2,
                                              float* __restrict__ outSpk,
                                              float* __restrict__ outMem2) {
#pragma clang fp contract(off)
    const int tid = threadIdx.x;                  // b*2 + o
    float mem = 0.0f;
    float cur[8], nxt[8];
#pragma unroll
    for (int k = 0; k < 8; ++k) cur[k] = h2[k * 256 + tid];
    for (int t0 = 0; t0 < TT; t0 += 8) {
#pragma unroll
        for (int k = 0; k < 8; ++k) {
            int tn = t0 + 8 + k;
            nxt[k] = (tn < TT) ? h2[tn * 256 + tid] : 0.0f;
        }
#pragma unroll
        for (int k = 0; k < 8; ++k) {
            float mm = 0.9f * mem;
            mm = mm + cur[k];
            float spk = (mm - 1.0f > 0.0f) ? 1.0f : 0.0f;
            mm = mm - spk;
            mem = mm;
            outSpk[(t0 + k) * 256 + tid] = spk;
        }
#pragma unroll
        for (int k = 0; k < 8; ++k) cur[k] = nxt[k];
    }
    outMem2[tid] = mem;
}

extern "C" void kernel_launch(void* const* d_in, const int* in_sizes, int n_in,
                              void* d_out, int out_size, void* d_ws, size_t ws_size,
                              hipStream_t stream) {
    const float* x  = (const float*)d_in[0];
    const float* W1 = (const float*)d_in[1];
    const float* b1 = (const float*)d_in[2];
    const float* W2 = (const float*)d_in[3];
    const float* b2 = (const float*)d_in[4];
    float* out = (float*)d_out;

    char* ws = (char*)d_ws;
    float*         W1T = (float*)(ws);                                 // 1 MB
    unsigned int*  cnt = (unsigned int*)(ws + (1 << 20));              // 512 KB
    unsigned char* idx = (unsigned char*)(ws + (1 << 20) + (1 << 19)); // 131072*slots

    // size the index lists to the workspace (fallback path covers overflow)
    size_t fixedB = (size_t)(1 << 20) + (1 << 19) + (1 << 20);
    size_t avail  = ws_size > fixedB ? ws_size - fixedB : 0;
    long   s      = (long)((avail / 131072) & ~(size_t)7);
    int slots = (int)(s > 96 ? 96 : (s < 8 ? 8 : s));

    float* h2 = (float*)(ws + (1 << 20) + (1 << 19) + (size_t)131072 * (size_t)slots); // 1 MB

    k_transpose<<<1024, 256, 0, stream>>>(W1, W1T);
    k_pack<<<131072, 256, 0, stream>>>(x, cnt, idx, slots);
    k_snn<<<256, 256, 0, stream>>>(W1T, cnt, idx, x, b1, out + OFF_HID, slots);
    k_h2<<<32768, 256, 0, stream>>>(out + OFF_HID, W2, b2, h2);
    k_scan<<<1, 256, 0, stream>>>(h2, out, out + OFF_MEM2);
}

// Round 6
// 1653.422 us; speedup vs baseline: 1.8012x; 1.8012x over previous
//
#include <hip/hip_runtime.h>
#include <hip/hip_bf16.h>
#include <stdint.h>

// SNN forward (snntorch Leaky, subtract reset), T=1024 B=128 NIN=256 HID=1024.
// d_out: out_spikes [T,B,2] | hidden_spikes [T,B,HID] | mem2_f [B,2]
//
// Round-6: timestep-paired b128 gather. Wave = 32 quads (128 j) for one b;
// lanes 0-31 gather timestep t, lanes 32-63 timestep t+1 (independent sums).
// One ds_read_b128 per active index serves 128 j of one t: full 1KB utility,
// zero redundant adds. Membrane: 4x v_permlane32_swap per 2t hands both h's
// to every lane; redundant 2-step membrane update; one float4 store at row
// t+half. Order per (t,j) stays bias -> ascending active i -> bit-exact.
// k_pack/k_h2/k_scan/k_transpose unchanged (proven absmax 0.0).

#define TT  1024
#define BB  128
#define NIN 256
#define HID 1024

#define OFF_HID  262144ULL
#define OFF_MEM2 134479872ULL

__global__ __launch_bounds__(256) void k_transpose(const float* __restrict__ W1,
                                                   float* __restrict__ W1T) {
    int idx = blockIdx.x * 256 + threadIdx.x;     // 262144 elements
    int j = idx & (HID - 1);
    int i = idx >> 10;
    W1T[(size_t)i * HID + j] = W1[(size_t)j * NIN + i];
}

__global__ __launch_bounds__(256) void k_pack(const float* __restrict__ x,
                                              unsigned int* __restrict__ cntArr,
                                              unsigned char* __restrict__ idxArr,
                                              int slots) {
    size_t tb = blockIdx.x;                       // T*B blocks, 256 threads = i
    int tid = threadIdx.x;
    int lane = tid & 63, w = tid >> 6;
    float v = x[tb * NIN + tid];
    bool act = v > 0.5f;
    unsigned long long m = __ballot(act);
    __shared__ unsigned int wc[4];
    __shared__ unsigned char sIdx[96];
    if (lane == 0) wc[w] = (unsigned int)__popcll(m);
    __syncthreads();
    unsigned int off = 0;
#pragma unroll
    for (int k = 0; k < 4; ++k) if (k < w) off += wc[k];
    unsigned int cnt = wc[0] + wc[1] + wc[2] + wc[3];
    unsigned int rank = off + (unsigned int)__popcll(m & ((1ull << lane) - 1));
    if (act && rank < (unsigned int)slots) sIdx[rank] = (unsigned char)tid;
    __syncthreads();
    if (tid * 4 < slots)
        ((unsigned int*)(idxArr + tb * (size_t)slots))[tid] = ((const unsigned int*)sIdx)[tid];
    if (tid == 0) cntArr[tb] = cnt;
}

// Workgroup = 4 waves = 4 b's sharing a 128-j chunk of W1T as [256 i][32 quads]
// float4 (128 KB LDS). q = lane&31 -> quad (4 j); half = lane>>5 -> t-parity.
// Grid = 32 bg x 8 jc = 256 wgs (1/CU).
__global__ __launch_bounds__(256, 1) void k_snn(const float* __restrict__ W1T,
                                                const unsigned int* __restrict__ cntArr,
                                                const unsigned char* __restrict__ idxArr,
                                                const float* __restrict__ x,
                                                const float* __restrict__ b1,
                                                float* __restrict__ outHid,
                                                int slots) {
#pragma clang fp contract(off)
    const int jc   = blockIdx.x & 7;
    const int bg   = blockIdx.x >> 3;
    const int lane = threadIdx.x & 63;
    const int wave = threadIdx.x >> 6;
    const int b    = (bg << 2) + wave;
    const int q    = lane & 31;                   // quad index within 128-j chunk
    const int half = lane >> 5;                   // 0: timestep t, 1: timestep t+1
    const int jq   = (jc << 7) + (q << 2);        // first j of this lane's quad

    __shared__ float4 sW4[NIN * 32];              // 128 KB: [i][quad]
    for (int p = threadIdx.x; p < NIN * 32; p += 256) {
        int i = p >> 5, qq = p & 31;
        sW4[p] = *reinterpret_cast<const float4*>(W1T + (size_t)i * HID + (jc << 7) + (qq << 2));
    }
    __syncthreads();

    float mem0 = 0.0f, mem1 = 0.0f, mem2 = 0.0f, mem3 = 0.0f;
    const float4 bs = *reinterpret_cast<const float4*>(b1 + jq);
    const int    ub = __builtin_amdgcn_readfirstlane(b);
    const int    sl = slots;

    int dwi = lane & 31;                          // dword slot of my half's list
    if (dwi * 4 >= sl) dwi = 0;                   // clamp (unused lanes)

    // prefetch lists for t=0 (half 0) / t=1 (half 1)
    size_t tb0 = (size_t)half * BB + ub;
    unsigned int cnt_v  = cntArr[tb0];
    unsigned int vIdx_v = ((const unsigned int*)(idxArr + tb0 * (size_t)sl))[dwi];

    for (int t = 0; t < TT; t += 2) {
        unsigned int ce = (unsigned int)__builtin_amdgcn_readlane((int)cnt_v, 0);
        unsigned int co = (unsigned int)__builtin_amdgcn_readlane((int)cnt_v, 32);
        unsigned int vIdx = vIdx_v;

        // prefetch t+2/t+3 (clamped)
        int tn = (t + 2 < TT) ? t + 2 : t;
        size_t tbn = (size_t)(tn + half) * BB + ub;
        cnt_v  = cntArr[tbn];
        vIdx_v = ((const unsigned int*)(idxArr + tbn * (size_t)sl))[dwi];

        float h0 = bs.x, h1 = bs.y, h2 = bs.z, h3 = bs.w;
        unsigned int le = ce < (unsigned int)sl ? ce : (unsigned int)sl;
        unsigned int lo = co < (unsigned int)sl ? co : (unsigned int)sl;
        unsigned int kmin  = le < lo ? le : lo;
        unsigned int kmax  = le > lo ? le : lo;
        unsigned int mylim = half ? lo : le;

        unsigned int k = 0;
        while (k + 4 <= kmin) {                   // both halves active, 4 idx/dword
            unsigned int de = (unsigned int)__builtin_amdgcn_readlane((int)vIdx, (int)(k >> 2));
            unsigned int dd = (unsigned int)__builtin_amdgcn_readlane((int)vIdx, (int)(k >> 2) + 32);
            unsigned int d  = half ? dd : de;     // my half's 4 indices
            unsigned int r0 = d & 255u, r1 = (d >> 8) & 255u;
            unsigned int r2 = (d >> 16) & 255u, r3 = d >> 24;
            float4 v0 = sW4[r0 * 32 + q];
            float4 v1 = sW4[r1 * 32 + q];
            float4 v2 = sW4[r2 * 32 + q];
            float4 v3 = sW4[r3 * 32 + q];
            h0 += v0.x; h1 += v0.y; h2 += v0.z; h3 += v0.w;   // ascending-i
            h0 += v1.x; h1 += v1.y; h2 += v1.z; h3 += v1.w;
            h0 += v2.x; h1 += v2.y; h2 += v2.z; h3 += v2.w;
            h0 += v3.x; h1 += v3.y; h2 += v3.z; h3 += v3.w;
            k += 4;
        }
        if (k < kmin) {                           // partial dword, both halves
            unsigned int de = (unsigned int)__builtin_amdgcn_readlane((int)vIdx, (int)(k >> 2));
            unsigned int dd = (unsigned int)__builtin_amdgcn_readlane((int)vIdx, (int)(k >> 2) + 32);
            unsigned int d  = half ? dd : de;
            for (; k < kmin; ++k) {
                unsigned int r = (d >> ((k & 3u) * 8u)) & 255u;
                float4 v = sW4[r * 32 + q];
                h0 += v.x; h1 += v.y; h2 += v.z; h3 += v.w;
            }
        }
        for (; k < kmax; ++k) {                   // longer half only (exec-masked)
            unsigned int de = (unsigned int)__builtin_amdgcn_readlane((int)vIdx, (int)(k >> 2));
            unsigned int dd = (unsigned int)__builtin_amdgcn_readlane((int)vIdx, (int)(k >> 2) + 32);
            unsigned int d  = half ? dd : de;
            unsigned int r  = (d >> ((k & 3u) * 8u)) & 255u;
            if (k < mylim) {
                float4 v = sW4[r * 32 + q];
                h0 += v.x; h1 += v.y; h2 += v.z; h3 += v.w;
            }
        }

        if (ce > (unsigned int)sl || co > (unsigned int)sl) {  // ~never: recompute both t's
            float f00 = bs.x, f01 = bs.y, f02 = bs.z, f03 = bs.w;
            float f10 = bs.x, f11 = bs.y, f12 = bs.z, f13 = bs.w;
#pragma unroll
            for (int tt = 0; tt < 2; ++tt) {
                const float* xr = x + ((size_t)(t + tt) * BB + ub) * NIN;
                float g0 = bs.x, g1 = bs.y, g2 = bs.z, g3 = bs.w;
                for (int w = 0; w < 4; ++w) {
                    unsigned long long m = __ballot(xr[(w << 6) + lane] > 0.5f);
                    while (m) {
                        int i = (w << 6) + __builtin_ctzll(m);
                        m &= m - 1;
                        float4 v = sW4[i * 32 + q];
                        g0 += v.x; g1 += v.y; g2 += v.z; g3 += v.w;
                    }
                }
                if (tt == 0) { f00 = g0; f01 = g1; f02 = g2; f03 = g3; }
                else         { f10 = g0; f11 = g1; f12 = g2; f13 = g3; }
            }
            h0 = half ? f10 : f00; h1 = half ? f11 : f01;
            h2 = half ? f12 : f02; h3 = half ? f13 : f03;
        }

        // exchange: aX = h(t) in all lanes, bX = h(t+1) in all lanes
        float a0 = h0, p0 = h0, a1 = h1, p1 = h1;
        float a2 = h2, p2 = h2, a3 = h3, p3 = h3;
        asm("v_permlane32_swap_b32 %0, %1" : "+v"(a0), "+v"(p0));
        asm("v_permlane32_swap_b32 %0, %1" : "+v"(a1), "+v"(p1));
        asm("v_permlane32_swap_b32 %0, %1" : "+v"(a2), "+v"(p2));
        asm("v_permlane32_swap_b32 %0, %1" : "+v"(a3), "+v"(p3));

        // two membrane steps (np fp32 semantics: mul, add separate), redundant
        // across halves so exec stays full.
        float mA0 = 0.9f * mem0; mA0 = mA0 + a0;
        float sA0 = (mA0 - 1.0f > 0.0f) ? 1.0f : 0.0f; mA0 = mA0 - sA0;
        float mB0 = 0.9f * mA0; mB0 = mB0 + p0;
        float sB0 = (mB0 - 1.0f > 0.0f) ? 1.0f : 0.0f; mem0 = mB0 - sB0;

        float mA1 = 0.9f * mem1; mA1 = mA1 + a1;
        float sA1 = (mA1 - 1.0f > 0.0f) ? 1.0f : 0.0f; mA1 = mA1 - sA1;
        float mB1 = 0.9f * mA1; mB1 = mB1 + p1;
        float sB1 = (mB1 - 1.0f > 0.0f) ? 1.0f : 0.0f; mem1 = mB1 - sB1;

        float mA2 = 0.9f * mem2; mA2 = mA2 + a2;
        float sA2 = (mA2 - 1.0f > 0.0f) ? 1.0f : 0.0f; mA2 = mA2 - sA2;
        float mB2 = 0.9f * mA2; mB2 = mB2 + p2;
        float sB2 = (mB2 - 1.0f > 0.0f) ? 1.0f : 0.0f; mem2 = mB2 - sB2;

        float mA3 = 0.9f * mem3; mA3 = mA3 + a3;
        float sA3 = (mA3 - 1.0f > 0.0f) ? 1.0f : 0.0f; mA3 = mA3 - sA3;
        float mB3 = 0.9f * mA3; mB3 = mB3 + p3;
        float sB3 = (mB3 - 1.0f > 0.0f) ? 1.0f : 0.0f; mem3 = mB3 - sB3;

        // half 0 stores row t (spkA), half 1 stores row t+1 (spkB)
        float4 sv;
        sv.x = half ? sB0 : sA0;
        sv.y = half ? sB1 : sA1;
        sv.z = half ? sB2 : sA2;
        sv.w = half ? sB3 : sA3;
        *reinterpret_cast<float4*>(outHid + ((size_t)(t + half) * BB + b) * HID + jq) = sv;
    }
}

// One wave per (t,b): bit-identical layer-2 tree to rounds 1-5:
// per chunk c (ascending 0..15): r = spk[c*64+lane]*W2[o][c*64+lane],
// xor-butterfly offs 32,16,8,4,2,1, accumulate; then + b2[o].
__global__ __launch_bounds__(256) void k_h2(const float* __restrict__ spk,
                                            const float* __restrict__ W2,
                                            const float* __restrict__ b2,
                                            float* __restrict__ h2) {
#pragma clang fp contract(off)
    const int lane = threadIdx.x & 63;
    const int wave = threadIdx.x >> 6;
    size_t tb = (size_t)blockIdx.x * 4 + wave;    // t*B + b
    const float* row = spk + tb * HID;
    float s0 = 0.0f, s1 = 0.0f;
#pragma unroll
    for (int c = 0; c < 16; ++c) {
        float v  = row[c * 64 + lane];
        float r0 = v * W2[c * 64 + lane];
        float r1 = v * W2[HID + c * 64 + lane];
#pragma unroll
        for (int off = 32; off > 0; off >>= 1) {
            r0 += __shfl_xor(r0, off, 64);
            r1 += __shfl_xor(r1, off, 64);
        }
        s0 += r0;
        s1 += r1;
    }
    s0 += b2[0];
    s1 += b2[1];
    if (lane == 0)
        *reinterpret_cast<float2*>(h2 + tb * 2) = make_float2(s0, s1);
}

__global__ __launch_bounds__(256) void k_scan(const float* __restrict__ h2,
                                              float* __restrict__ outSpk,
                                              float* __restrict__ outMem2) {
#pragma clang fp contract(off)
    const int tid = threadIdx.x;                  // b*2 + o
    float mem = 0.0f;
    float cur[8], nxt[8];
#pragma unroll
    for (int k = 0; k < 8; ++k) cur[k] = h2[k * 256 + tid];
    for (int t0 = 0; t0 < TT; t0 += 8) {
#pragma unroll
        for (int k = 0; k < 8; ++k) {
            int tn = t0 + 8 + k;
            nxt[k] = (tn < TT) ? h2[tn * 256 + tid] : 0.0f;
        }
#pragma unroll
        for (int k = 0; k < 8; ++k) {
            float mm = 0.9f * mem;
            mm = mm + cur[k];
            float spk = (mm - 1.0f > 0.0f) ? 1.0f : 0.0f;
            mm = mm - spk;
            mem = mm;
            outSpk[(t0 + k) * 256 + tid] = spk;
        }
#pragma unroll
        for (int k = 0; k < 8; ++k) cur[k] = nxt[k];
    }
    outMem2[tid] = mem;
}

extern "C" void kernel_launch(void* const* d_in, const int* in_sizes, int n_in,
                              void* d_out, int out_size, void* d_ws, size_t ws_size,
                              hipStream_t stream) {
    const float* x  = (const float*)d_in[0];
    const float* W1 = (const float*)d_in[1];
    const float* b1 = (const float*)d_in[2];
    const float* W2 = (const float*)d_in[3];
    const float* b2 = (const float*)d_in[4];
    float* out = (float*)d_out;

    char* ws = (char*)d_ws;
    float*         W1T = (float*)(ws);                                 // 1 MB
    unsigned int*  cnt = (unsigned int*)(ws + (1 << 20));              // 512 KB
    unsigned char* idx = (unsigned char*)(ws + (1 << 20) + (1 << 19)); // 131072*slots

    // size the index lists to the workspace (fallback path covers overflow)
    size_t fixedB = (size_t)(1 << 20) + (1 << 19) + (1 << 20);
    size_t avail  = ws_size > fixedB ? ws_size - fixedB : 0;
    long   s      = (long)((avail / 131072) & ~(size_t)7);
    int slots = (int)(s > 96 ? 96 : (s < 8 ? 8 : s));

    float* h2 = (float*)(ws + (1 << 20) + (1 << 19) + (size_t)131072 * (size_t)slots); // 1 MB

    k_transpose<<<1024, 256, 0, stream>>>(W1, W1T);
    k_pack<<<131072, 256, 0, stream>>>(x, cnt, idx, slots);
    k_snn<<<256, 256, 0, stream>>>(W1T, cnt, idx, x, b1, out + OFF_HID, slots);
    k_h2<<<32768, 256, 0, stream>>>(out + OFF_HID, W2, b2, h2);
    k_scan<<<1, 256, 0, stream>>>(h2, out, out + OFF_MEM2);
}

// Round 7
// 1232.633 us; speedup vs baseline: 2.4160x; 1.3414x over previous
//
#include <hip/hip_runtime.h>
#include <hip/hip_bf16.h>
#include <stdint.h>

// SNN forward (snntorch Leaky, subtract reset), T=1024 B=128 NIN=256 HID=1024.
// d_out: out_spikes [T,B,2] | hidden_spikes [T,B,HID] | mem2_f [B,2]
//
// Round-7: 4 timestep-groups per wave. lane = (s=lane>>4, q=lane&15); wave
// covers 64 j (16 quads) for timesteps t..t+3. Tile = [257 i][16 quads] f4
// (64.3 KB; row 256 = zeros for tail predication, +0.0f adds are FP-exact)
// -> 2 wg/CU, 2 waves/SIMD: DS pipe latency actually hidden (round-6 failed
// at 1 wave/SIMD). One ds_read_b128 per active index per 4t-group, zero
// redundancy, conflict-free (4x256B segments = the 8-round b128 minimum).
// Cross-group membrane exchange via per-wave LDS scratch (1 write+4 reads).
// Per-(t,j) FP order: bias -> ascending active i -> bit-exact (absmax 0.0
// across all prior rounds). k_pack/k_h2/k_scan/k_transpose unchanged.

#define TT  1024
#define BB  128
#define NIN 256
#define HID 1024

#define OFF_HID  262144ULL
#define OFF_MEM2 134479872ULL

__global__ __launch_bounds__(256) void k_transpose(const float* __restrict__ W1,
                                                   float* __restrict__ W1T) {
    int idx = blockIdx.x * 256 + threadIdx.x;     // 262144 elements
    int j = idx & (HID - 1);
    int i = idx >> 10;
    W1T[(size_t)i * HID + j] = W1[(size_t)j * NIN + i];
}

__global__ __launch_bounds__(256) void k_pack(const float* __restrict__ x,
                                              unsigned int* __restrict__ cntArr,
                                              unsigned char* __restrict__ idxArr,
                                              int slots) {
    size_t tb = blockIdx.x;                       // T*B blocks, 256 threads = i
    int tid = threadIdx.x;
    int lane = tid & 63, w = tid >> 6;
    float v = x[tb * NIN + tid];
    bool act = v > 0.5f;
    unsigned long long m = __ballot(act);
    __shared__ unsigned int wc[4];
    __shared__ unsigned char sIdx[96];
    if (lane == 0) wc[w] = (unsigned int)__popcll(m);
    __syncthreads();
    unsigned int off = 0;
#pragma unroll
    for (int k = 0; k < 4; ++k) if (k < w) off += wc[k];
    unsigned int cnt = wc[0] + wc[1] + wc[2] + wc[3];
    unsigned int rank = off + (unsigned int)__popcll(m & ((1ull << lane) - 1));
    if (act && rank < (unsigned int)slots) sIdx[rank] = (unsigned char)tid;
    __syncthreads();
    if (tid * 4 < slots)
        ((unsigned int*)(idxArr + tb * (size_t)slots))[tid] = ((const unsigned int*)sIdx)[tid];
    if (tid == 0) cntArr[tb] = cnt;
}

// Workgroup = 4 waves = 4 b's sharing a 64-j chunk of W1T as [257 i][16 quads]
// float4 (64.3 KB LDS). Grid = 32 bg x 16 jc = 512 wgs -> 2 wg/CU.
__global__ __launch_bounds__(256) void k_snn(const float* __restrict__ W1T,
                                             const unsigned int* __restrict__ cntArr,
                                             const unsigned char* __restrict__ idxArr,
                                             const float* __restrict__ x,
                                             const float* __restrict__ b1,
                                             float* __restrict__ outHid,
                                             int slots) {
#pragma clang fp contract(off)
    const int jc   = blockIdx.x & 15;
    const int bg   = blockIdx.x >> 4;
    const int tid  = threadIdx.x;
    const int lane = tid & 63;
    const int wave = tid >> 6;
    const int b    = (bg << 2) + wave;
    const int q    = lane & 15;                   // quad (4 j) within 64-j chunk
    const int s    = lane >> 4;                   // t-subgroup 0..3
    const int jq   = (jc << 6) + (q << 2);

    __shared__ float4 sW4[257 * 16];              // 64.3 KB; row 256 = zeros
    __shared__ float4 sEx[4][64];                 // per-wave exchange scratch

    for (int p = tid; p < NIN * 16; p += 256) {
        int i = p >> 4, qq = p & 15;
        sW4[p] = *reinterpret_cast<const float4*>(W1T + (size_t)i * HID + (jc << 6) + (qq << 2));
    }
    if (tid < 16) sW4[256 * 16 + tid] = make_float4(0.f, 0.f, 0.f, 0.f);
    __syncthreads();

    float mem0 = 0.f, mem1 = 0.f, mem2 = 0.f, mem3 = 0.f;
    const float4 bs = *reinterpret_cast<const float4*>(b1 + jq);
    const int ub = __builtin_amdgcn_readfirstlane(b);
    const int sl = slots;
    const int dwTot = sl >> 2;                    // dwords per list (mult of 2)
    int dwA = q;            if (dwA >= dwTot) dwA = dwTot - 1;
    int dwB = 16 + (q & 7); if (dwB >= dwTot) dwB = dwTot - 1;

    const bool sLo   = (s < 2);
    const bool sEven = ((s & 1) == 0);

    // prefetch lists for t = 0..3 (each group its own t)
    size_t tb0 = (size_t)s * BB + ub;
    unsigned int cnt_v = cntArr[tb0];
    {
        const unsigned int* lp = (const unsigned int*)(idxArr + tb0 * (size_t)sl);
        // nothing
    }
    unsigned int vA_v = ((const unsigned int*)(idxArr + tb0 * (size_t)sl))[dwA];
    unsigned int vB_v = ((const unsigned int*)(idxArr + tb0 * (size_t)sl))[dwB];

    for (int t = 0; t < TT; t += 4) {
        unsigned int cnt = cnt_v, vA = vA_v, vB = vB_v;

        // prefetch t+4 (clamped)
        int tn = (t + 4 < TT) ? t + 4 : t;
        size_t tbn = (size_t)(tn + s) * BB + ub;
        cnt_v = cntArr[tbn];
        const unsigned int* lpn = (const unsigned int*)(idxArr + tbn * (size_t)sl);
        vA_v = lpn[dwA];
        vB_v = lpn[dwB];

        unsigned int mylim = cnt < (unsigned int)sl ? cnt : (unsigned int)sl;
        int l0 = __builtin_amdgcn_readlane((int)mylim, 0);
        int l1 = __builtin_amdgcn_readlane((int)mylim, 16);
        int l2 = __builtin_amdgcn_readlane((int)mylim, 32);
        int l3 = __builtin_amdgcn_readlane((int)mylim, 48);
        int kmax = l0 > l1 ? l0 : l1;
        kmax = kmax > l2 ? kmax : l2;
        kmax = kmax > l3 ? kmax : l3;

        float4 e0, e1, e2, e3;                    // h(t+0..t+3) for quad q

        if (!__any((int)(cnt > (unsigned int)sl))) {
            float h0 = bs.x, h1 = bs.y, h2 = bs.z, h3 = bs.w;
            int kA = kmax < 64 ? kmax : 64;
            for (int k = 0; k < kA; k += 4) {
                int w = k >> 2;
                unsigned d0 = (unsigned)__builtin_amdgcn_readlane((int)vA, w);
                unsigned d1 = (unsigned)__builtin_amdgcn_readlane((int)vA, 16 + w);
                unsigned d2 = (unsigned)__builtin_amdgcn_readlane((int)vA, 32 + w);
                unsigned d3 = (unsigned)__builtin_amdgcn_readlane((int)vA, 48 + w);
                unsigned dl = sEven ? d0 : d1;
                unsigned dh = sEven ? d2 : d3;
                unsigned d  = sLo ? dl : dh;      // my group's 4 indices
#pragma unroll
                for (int i2 = 0; i2 < 4; ++i2) {
                    unsigned row = ((unsigned)(k + i2) < mylim) ? ((d >> (8 * i2)) & 255u) : 256u;
                    float4 v = sW4[row * 16 + q];
                    h0 += v.x; h1 += v.y; h2 += v.z; h3 += v.w;   // ascending-i
                }
            }
            for (int k = 64; k < kmax; k += 4) {
                int w = (k >> 2) - 16;
                unsigned d0 = (unsigned)__builtin_amdgcn_readlane((int)vB, w);
                unsigned d1 = (unsigned)__builtin_amdgcn_readlane((int)vB, 16 + w);
                unsigned d2 = (unsigned)__builtin_amdgcn_readlane((int)vB, 32 + w);
                unsigned d3 = (unsigned)__builtin_amdgcn_readlane((int)vB, 48 + w);
                unsigned dl = sEven ? d0 : d1;
                unsigned dh = sEven ? d2 : d3;
                unsigned d  = sLo ? dl : dh;
#pragma unroll
                for (int i2 = 0; i2 < 4; ++i2) {
                    unsigned row = ((unsigned)(k + i2) < mylim) ? ((d >> (8 * i2)) & 255u) : 256u;
                    float4 v = sW4[row * 16 + q];
                    h0 += v.x; h1 += v.y; h2 += v.z; h3 += v.w;
                }
            }
            // exchange: every lane gets h(t+0..t+3) for its quad (same wave,
            // per-wave scratch; compiler inserts the lgkmcnt waits)
            sEx[wave][lane] = make_float4(h0, h1, h2, h3);
            e0 = sEx[wave][q];
            e1 = sEx[wave][16 + q];
            e2 = sEx[wave][32 + q];
            e3 = sEx[wave][48 + q];
        } else {
            // ~never: some count exceeds slots -> recompute all 4 t's from x
#pragma unroll
            for (int tt = 0; tt < 4; ++tt) {
                const float* xr = x + ((size_t)(t + tt) * BB + ub) * NIN;
                float g0 = bs.x, g1 = bs.y, g2 = bs.z, g3 = bs.w;
                for (int w2 = 0; w2 < 4; ++w2) {
                    unsigned long long m = __ballot(xr[(w2 << 6) + lane] > 0.5f);
                    while (m) {
                        int i = (w2 << 6) + __builtin_ctzll(m);
                        m &= m - 1;
                        float4 v = sW4[i * 16 + q];
                        g0 += v.x; g1 += v.y; g2 += v.z; g3 += v.w;
                    }
                }
                if      (tt == 0) e0 = make_float4(g0, g1, g2, g3);
                else if (tt == 1) e1 = make_float4(g0, g1, g2, g3);
                else if (tt == 2) e2 = make_float4(g0, g1, g2, g3);
                else              e3 = make_float4(g0, g1, g2, g3);
            }
        }

        // 4 membrane steps (np fp32 semantics: mul, add separate), redundant
        // across all lanes so exec stays full.
#define MSTEP(hv, memv, spv) { float mm_ = 0.9f * (memv); mm_ = mm_ + (hv);     \
        spv = (mm_ - 1.0f > 0.0f) ? 1.0f : 0.0f; memv = mm_ - spv; }
        float sA0, sA1, sA2, sA3, sB0, sB1, sB2, sB3;
        float sC0, sC1, sC2, sC3, sD0, sD1, sD2, sD3;
        MSTEP(e0.x, mem0, sA0) MSTEP(e0.y, mem1, sA1) MSTEP(e0.z, mem2, sA2) MSTEP(e0.w, mem3, sA3)
        MSTEP(e1.x, mem0, sB0) MSTEP(e1.y, mem1, sB1) MSTEP(e1.z, mem2, sB2) MSTEP(e1.w, mem3, sB3)
        MSTEP(e2.x, mem0, sC0) MSTEP(e2.y, mem1, sC1) MSTEP(e2.z, mem2, sC2) MSTEP(e2.w, mem3, sC3)
        MSTEP(e3.x, mem0, sD0) MSTEP(e3.y, mem1, sD1) MSTEP(e3.z, mem2, sD2) MSTEP(e3.w, mem3, sD3)
#undef MSTEP

        // lane stores its own group's row (t+s)
        float4 sv;
        sv.x = sLo ? (sEven ? sA0 : sB0) : (sEven ? sC0 : sD0);
        sv.y = sLo ? (sEven ? sA1 : sB1) : (sEven ? sC1 : sD1);
        sv.z = sLo ? (sEven ? sA2 : sB2) : (sEven ? sC2 : sD2);
        sv.w = sLo ? (sEven ? sA3 : sB3) : (sEven ? sC3 : sD3);
        *reinterpret_cast<float4*>(outHid + ((size_t)(t + s) * BB + b) * HID + jq) = sv;
    }
}

// One wave per (t,b): bit-identical layer-2 tree to rounds 1-6:
// per chunk c (ascending 0..15): r = spk[c*64+lane]*W2[o][c*64+lane],
// xor-butterfly offs 32,16,8,4,2,1, accumulate; then + b2[o].
__global__ __launch_bounds__(256) void k_h2(const float* __restrict__ spk,
                                            const float* __restrict__ W2,
                                            const float* __restrict__ b2,
                                            float* __restrict__ h2) {
#pragma clang fp contract(off)
    const int lane = threadIdx.x & 63;
    const int wave = threadIdx.x >> 6;
    size_t tb = (size_t)blockIdx.x * 4 + wave;    // t*B + b
    const float* row = spk + tb * HID;
    float s0 = 0.0f, s1 = 0.0f;
#pragma unroll
    for (int c = 0; c < 16; ++c) {
        float v  = row[c * 64 + lane];
        float r0 = v * W2[c * 64 + lane];
        float r1 = v * W2[HID + c * 64 + lane];
#pragma unroll
        for (int off = 32; off > 0; off >>= 1) {
            r0 += __shfl_xor(r0, off, 64);
            r1 += __shfl_xor(r1, off, 64);
        }
        s0 += r0;
        s1 += r1;
    }
    s0 += b2[0];
    s1 += b2[1];
    if (lane == 0)
        *reinterpret_cast<float2*>(h2 + tb * 2) = make_float2(s0, s1);
}

__global__ __launch_bounds__(256) void k_scan(const float* __restrict__ h2,
                                              float* __restrict__ outSpk,
                                              float* __restrict__ outMem2) {
#pragma clang fp contract(off)
    const int tid = threadIdx.x;                  // b*2 + o
    float mem = 0.0f;
    float cur[8], nxt[8];
#pragma unroll
    for (int k = 0; k < 8; ++k) cur[k] = h2[k * 256 + tid];
    for (int t0 = 0; t0 < TT; t0 += 8) {
#pragma unroll
        for (int k = 0; k < 8; ++k) {
            int tn = t0 + 8 + k;
            nxt[k] = (tn < TT) ? h2[tn * 256 + tid] : 0.0f;
        }
#pragma unroll
        for (int k = 0; k < 8; ++k) {
            float mm = 0.9f * mem;
            mm = mm + cur[k];
            float spk = (mm - 1.0f > 0.0f) ? 1.0f : 0.0f;
            mm = mm - spk;
            mem = mm;
            outSpk[(t0 + k) * 256 + tid] = spk;
        }
#pragma unroll
        for (int k = 0; k < 8; ++k) cur[k] = nxt[k];
    }
    outMem2[tid] = mem;
}

extern "C" void kernel_launch(void* const* d_in, const int* in_sizes, int n_in,
                              void* d_out, int out_size, void* d_ws, size_t ws_size,
                              hipStream_t stream) {
    const float* x  = (const float*)d_in[0];
    const float* W1 = (const float*)d_in[1];
    const float* b1 = (const float*)d_in[2];
    const float* W2 = (const float*)d_in[3];
    const float* b2 = (const float*)d_in[4];
    float* out = (float*)d_out;

    char* ws = (char*)d_ws;
    float*         W1T = (float*)(ws);                                 // 1 MB
    unsigned int*  cnt = (unsigned int*)(ws + (1 << 20));              // 512 KB
    unsigned char* idx = (unsigned char*)(ws + (1 << 20) + (1 << 19)); // 131072*slots

    // size the index lists to the workspace (fallback path covers overflow)
    size_t fixedB = (size_t)(1 << 20) + (1 << 19) + (1 << 20);
    size_t avail  = ws_size > fixedB ? ws_size - fixedB : 0;
    long   s      = (long)((avail / 131072) & ~(size_t)7);
    int slots = (int)(s > 96 ? 96 : (s < 8 ? 8 : s));

    float* h2 = (float*)(ws + (1 << 20) + (1 << 19) + (size_t)131072 * (size_t)slots); // 1 MB

    k_transpose<<<1024, 256, 0, stream>>>(W1, W1T);
    k_pack<<<131072, 256, 0, stream>>>(x, cnt, idx, slots);
    k_snn<<<512, 256, 0, stream>>>(W1T, cnt, idx, x, b1, out + OFF_HID, slots);
    k_h2<<<32768, 256, 0, stream>>>(out + OFF_HID, W2, b2, h2);
    k_scan<<<1, 256, 0, stream>>>(h2, out, out + OFF_MEM2);
}